// Round 1
// baseline (324.061 us; speedup 1.0000x reference)
//
#include <hip/hip_runtime.h>
#include <hip/hip_bf16.h>
#include <math.h>

typedef short s16x4 __attribute__((ext_vector_type(4)));
typedef short bf16x8 __attribute__((ext_vector_type(8)));
typedef float f32x16 __attribute__((ext_vector_type(16)));

#define C_IN 273
#define C_OUT 270
#define T_DIM 2048
#define KP 288            // padded C_in (9 chunks of 32, 18 MFMA k-steps of 16)
#define APR_STRIDE 288
#define APR_ROWS 320

// workspace byte offsets
#define WS_COS 0u
#define WS_SIN 1118208u          // 273*1024*4
#define WS_PART 2236416u         // + 273*1024*4
#define WS_APERM 4743168u        // + 8*272*288*4

#define ALD_STRIDE 592           // bytes per a_lds row (296 bf16; odd-ish bank stride)
#define A_LDS_BYTES (64 * ALD_STRIDE)   // 37888
#define XBUF_BYTES 16384                // 32k x 256t bf16, subtiled [ks8][tb16][4][16]

__device__ __forceinline__ short f2bf(float f) {
  __hip_bfloat16 h = __float2bfloat16(f);
  short r; __builtin_memcpy(&r, &h, 2); return r;
}

// ---------------- kernel 1a: Fourier basis ----------------
__global__ void k_basis(const float* __restrict__ x, const float* __restrict__ y,
                        float* __restrict__ cosb, float* __restrict__ sinb) {
  const int i = blockIdx.x;            // 0..272
  const float xi = x[i], yi = y[i];
  const int base = threadIdx.x * 4;
  #pragma unroll
  for (int j = 0; j < 4; ++j) {
    const int kl = base + j;           // index = (l-1)*32 + (k-1)
    const float kf = (float)((kl & 31) + 1);
    const float lf = (float)((kl >> 5) + 1);
    const float ph = 6.28318530717958647692f * (kf * xi + lf * yi);
    float sn, cs;
    sincosf(ph, &sn, &cs);
    cosb[(size_t)i * 1024 + kl] = cs;
    sinb[(size_t)i * 1024 + kl] = sn;
  }
}

// ---------------- kernel 1b: logits partials (kl-chunked) ----------------
__global__ __launch_bounds__(256) void k_logits(const float* __restrict__ zr,
    const float* __restrict__ zi, const float* __restrict__ cosb,
    const float* __restrict__ sinb, float* __restrict__ part) {
  const int tx = threadIdx.x & 15, ty = threadIdx.x >> 4;
  const int ibase = blockIdx.x * 64 + tx * 4;
  const int obase = blockIdx.y * 64 + ty * 4;
  const int kl0 = (int)blockIdx.z * 128;
  int oc[4], ic[4];
  #pragma unroll
  for (int a = 0; a < 4; ++a) {
    oc[a] = min(obase + a, C_OUT - 1);
    ic[a] = min(ibase + a, C_IN - 1);
  }
  float acc[4][4] = {};
  for (int kl = kl0; kl < kl0 + 128; kl += 4) {
    float4 zr4[4], zi4[4], cb4[4], sb4[4];
    #pragma unroll
    for (int a = 0; a < 4; ++a) {
      zr4[a] = *(const float4*)(zr + (size_t)oc[a] * 1024 + kl);
      zi4[a] = *(const float4*)(zi + (size_t)oc[a] * 1024 + kl);
    }
    #pragma unroll
    for (int b = 0; b < 4; ++b) {
      cb4[b] = *(const float4*)(cosb + (size_t)ic[b] * 1024 + kl);
      sb4[b] = *(const float4*)(sinb + (size_t)ic[b] * 1024 + kl);
    }
    #pragma unroll
    for (int a = 0; a < 4; ++a)
      #pragma unroll
      for (int b = 0; b < 4; ++b)
        acc[a][b] += zr4[a].x * cb4[b].x + zr4[a].y * cb4[b].y
                   + zr4[a].z * cb4[b].z + zr4[a].w * cb4[b].w
                   + zi4[a].x * sb4[b].x + zi4[a].y * sb4[b].y
                   + zi4[a].z * sb4[b].z + zi4[a].w * sb4[b].w;
  }
  #pragma unroll
  for (int a = 0; a < 4; ++a)
    #pragma unroll
    for (int b = 0; b < 4; ++b) {
      const int o = obase + a, i = ibase + b;
      if (o < C_OUT && i < C_IN)
        part[((size_t)blockIdx.z * 272 + o) * 288 + i] = acc[a][b];
    }
}

// ---------------- kernel 1c: mask + softmax + permuted bf16 store ----------------
// a_perm[o][s] = a[o][k(s)], k(s) = (s&~3) | ((s&3) ^ ((s>>2)&3))   (involution)
__global__ __launch_bounds__(256) void k_softmax(const float* __restrict__ part,
    const float* __restrict__ x, const float* __restrict__ y,
    const float* __restrict__ xdp, const float* __restrict__ ydp,
    __hip_bfloat16* __restrict__ aperm) {
  const int o = blockIdx.x;            // 0..319
  const int tid = threadIdx.x;
  if (o >= C_OUT) {
    for (int s = tid; s < KP; s += 256)
      aperm[(size_t)o * APR_STRIDE + s] = __float2bfloat16(0.f);
    return;
  }
  __shared__ float red[8];
  const float xd = xdp[0], yd = ydp[0];
  const int i0 = tid, i1 = tid + 256;
  float v0, v1 = 0.f;
  {
    float s = 0.f;
    #pragma unroll
    for (int c = 0; c < 8; ++c) s += part[((size_t)c * 272 + o) * 288 + i0];
    const float dx = xd - x[i0], dy = yd - y[i0];
    v0 = (dx * dx + dy * dy < 0.1f) ? 0.f : s;
  }
  const bool has1 = (i1 < C_IN);
  if (has1) {
    float s = 0.f;
    #pragma unroll
    for (int c = 0; c < 8; ++c) s += part[((size_t)c * 272 + o) * 288 + i1];
    const float dx = xd - x[i1], dy = yd - y[i1];
    v1 = (dx * dx + dy * dy < 0.1f) ? 0.f : s;
  }
  float mv = has1 ? fmaxf(v0, v1) : v0;
  #pragma unroll
  for (int off = 32; off >= 1; off >>= 1) mv = fmaxf(mv, __shfl_down(mv, off));
  if ((tid & 63) == 0) red[tid >> 6] = mv;
  __syncthreads();
  const float M = fmaxf(fmaxf(red[0], red[1]), fmaxf(red[2], red[3]));
  const float e0 = expf(v0 - M);
  const float e1 = has1 ? expf(v1 - M) : 0.f;
  float sv = e0 + e1;
  #pragma unroll
  for (int off = 32; off >= 1; off >>= 1) sv += __shfl_down(sv, off);
  __syncthreads();
  if ((tid & 63) == 0) red[4 + (tid >> 6)] = sv;
  __syncthreads();
  const float S = red[4] + red[5] + red[6] + red[7];
  const float inv = 1.0f / S;
  {
    const int s = (i0 & ~3) | ((i0 & 3) ^ ((i0 >> 2) & 3));
    aperm[(size_t)o * APR_STRIDE + s] = __float2bfloat16(e0 * inv);
  }
  if (i1 < KP) {
    const int s = (i1 & ~3) | ((i1 & 3) ^ ((i1 >> 2) & 3));
    aperm[(size_t)o * APR_STRIDE + s] = __float2bfloat16(has1 ? e1 * inv : 0.f);
  }
}

// ---------------- kernel 2: out[b] = a @ X[b] (bf16 MFMA) ----------------
__device__ __forceinline__ void load_chunk(const float* __restrict__ Xb, int ch,
                                           int t_base, int tid, float4 (&r)[2][4]) {
  #pragma unroll
  for (int h = 0; h < 2; ++h) {
    const int s = tid + h * 256;
    const int k4 = s & 7, t4 = s >> 3;
    const int t = t_base + t4 * 4;
    #pragma unroll
    for (int rr = 0; rr < 4; ++rr) {
      const int i = ch * 32 + k4 * 4 + rr;
      float4 v = make_float4(0.f, 0.f, 0.f, 0.f);
      if (i < C_IN) v = *(const float4*)(Xb + (size_t)i * T_DIM + t);
      r[h][rr] = v;
    }
  }
}

__device__ __forceinline__ void write_chunk(char* __restrict__ xb, int tid,
                                            const float4 (&r)[2][4]) {
  #pragma unroll
  for (int h = 0; h < 2; ++h) {
    const int s = tid + h * 256;
    const int k4 = s & 7, t4 = s >> 3;
    const int tb = t4 >> 2, c4 = t4 & 3;
    #pragma unroll
    for (int rr = 0; rr < 4; ++rr) {
      const int j = rr ^ (k4 & 3);   // in-tile row swizzle (bank spread); compensated in a_perm
      s16x4 p;
      p[0] = f2bf(r[h][rr].x); p[1] = f2bf(r[h][rr].y);
      p[2] = f2bf(r[h][rr].z); p[3] = f2bf(r[h][rr].w);
      *(s16x4*)(xb + (k4 * 16 + tb) * 128 + j * 32 + c4 * 8) = p;
    }
  }
}

__global__ __launch_bounds__(256) void k_gemm(const float* __restrict__ X,
    const __hip_bfloat16* __restrict__ aperm, float* __restrict__ out) {
  __shared__ __align__(16) char smem[A_LDS_BYTES + 2 * XBUF_BYTES];
  const int tid = threadIdx.x;
  const int lane = tid & 63, w = tid >> 6;
  const int o_base = blockIdx.y * 64;
  const int t_base = blockIdx.x * 256;
  const float* Xb = X + (size_t)blockIdx.z * C_IN * T_DIM;

  // stage a tile: 64 rows x 288 slots bf16, row stride 592 B. Fully coalesced reads.
  {
    const int row = tid >> 2, q = tid & 3;
    const float4* src = (const float4*)((const char*)(aperm + (size_t)(o_base + row) * APR_STRIDE) + q * 144);
    float4* dst = (float4*)(smem + row * ALD_STRIDE + q * 144);
    #pragma unroll
    for (int v = 0; v < 9; ++v) dst[v] = src[v];
  }

  f32x16 acc[2][2] = {};
  const unsigned smem_u = (unsigned)(unsigned long long)(uintptr_t)smem;  // low 32 = LDS offset
  const unsigned xlds0 = smem_u + A_LDS_BYTES;
  const int lg = lane >> 4, l16 = lane & 15, l32 = lane & 31, lh = lane >> 5;
  // B-region base per lane: region(g) = tile(ks = (g>>1)*2 + rd + kk/4, tb = w*4 + n*2 + (g&1))
  const unsigned bconst = (unsigned)((lg >> 1) * 4096 + (lg & 1) * 128 + w * 512 + l16 * 8);

  float4 regs[2][4];
  load_chunk(Xb, 0, t_base, tid, regs);
  write_chunk(smem + A_LDS_BYTES, tid, regs);
  __syncthreads();

  #pragma unroll 2
  for (int ch = 0; ch < 9; ++ch) {
    const int buf = ch & 1;
    if (ch < 8) load_chunk(Xb, ch + 1, t_base, tid, regs);   // issue early, consume late
    {
      const unsigned xb = xlds0 + buf * XBUF_BYTES + bconst;
      const char* arow0 = smem + l32 * ALD_STRIDE + (ch * 32) * 2 + lh * 16;
      #pragma unroll
      for (int kk = 0; kk < 32; kk += 16) {
        bf16x8 A0 = *(const bf16x8*)(arow0 + kk * 2);
        bf16x8 A1 = *(const bf16x8*)(arow0 + 32 * ALD_STRIDE + kk * 2);
        s16x4 t0, t1, t2, t3;
        const unsigned a0 = xb + kk * 512;
        asm volatile("ds_read_b64_tr_b16 %0, %1" : "=v"(t0) : "v"(a0));
        asm volatile("ds_read_b64_tr_b16 %0, %1 offset:2048" : "=v"(t1) : "v"(a0));
        asm volatile("ds_read_b64_tr_b16 %0, %1 offset:256" : "=v"(t2) : "v"(a0));
        asm volatile("ds_read_b64_tr_b16 %0, %1 offset:2304" : "=v"(t3) : "v"(a0));
        asm volatile("s_waitcnt lgkmcnt(0)" ::: "memory");
        __builtin_amdgcn_sched_barrier(0);
        bf16x8 B0, B1;
        B0[0] = t0[0]; B0[1] = t0[1]; B0[2] = t0[2]; B0[3] = t0[3];
        B0[4] = t1[0]; B0[5] = t1[1]; B0[6] = t1[2]; B0[7] = t1[3];
        B1[0] = t2[0]; B1[1] = t2[1]; B1[2] = t2[2]; B1[3] = t2[3];
        B1[4] = t3[0]; B1[5] = t3[1]; B1[6] = t3[2]; B1[7] = t3[3];
        acc[0][0] = __builtin_amdgcn_mfma_f32_32x32x16_bf16(A0, B0, acc[0][0], 0, 0, 0);
        acc[0][1] = __builtin_amdgcn_mfma_f32_32x32x16_bf16(A0, B1, acc[0][1], 0, 0, 0);
        acc[1][0] = __builtin_amdgcn_mfma_f32_32x32x16_bf16(A1, B0, acc[1][0], 0, 0, 0);
        acc[1][1] = __builtin_amdgcn_mfma_f32_32x32x16_bf16(A1, B1, acc[1][1], 0, 0, 0);
      }
    }
    if (ch < 8) write_chunk(smem + A_LDS_BYTES + (buf ^ 1) * XBUF_BYTES, tid, regs);
    __syncthreads();
  }

  // epilogue: C/D layout (32x32): col = l&31, row = (r&3) + 8*(r>>2) + 4*(l>>5)
  float* outb = out + (size_t)blockIdx.z * C_OUT * T_DIM;
  #pragma unroll
  for (int m = 0; m < 2; ++m)
    #pragma unroll
    for (int n = 0; n < 2; ++n)
      #pragma unroll
      for (int r = 0; r < 16; ++r) {
        const int o = o_base + m * 32 + (r & 3) + 8 * (r >> 2) + 4 * lh;
        if (o < C_OUT) {
          const int t = t_base + w * 64 + n * 32 + l32;
          outb[(size_t)o * T_DIM + t] = acc[m][n][r];
        }
      }
}

extern "C" void kernel_launch(void* const* d_in, const int* in_sizes, int n_in,
                              void* d_out, int out_size, void* d_ws, size_t ws_size,
                              hipStream_t stream) {
  const float* X  = (const float*)d_in[0];
  const float* zr = (const float*)d_in[1];
  const float* zi = (const float*)d_in[2];
  const float* x  = (const float*)d_in[3];
  const float* y  = (const float*)d_in[4];
  const float* xd = (const float*)d_in[5];
  const float* yd = (const float*)d_in[6];
  float* out = (float*)d_out;
  char* ws = (char*)d_ws;
  float* cosb = (float*)(ws + WS_COS);
  float* sinb = (float*)(ws + WS_SIN);
  float* part = (float*)(ws + WS_PART);
  __hip_bfloat16* aperm = (__hip_bfloat16*)(ws + WS_APERM);

  k_basis<<<dim3(273), dim3(256), 0, stream>>>(x, y, cosb, sinb);
  k_logits<<<dim3(5, 5, 8), dim3(256), 0, stream>>>(zr, zi, cosb, sinb, part);
  k_softmax<<<dim3(APR_ROWS), dim3(256), 0, stream>>>(part, x, y, xd, yd, aperm);
  k_gemm<<<dim3(8, 5, 128), dim3(256), 0, stream>>>(X, aperm, out);
}